// Round 1
// baseline (1494.384 us; speedup 1.0000x reference)
//
#include <hip/hip_runtime.h>

#define BB 2
#define SS 1024
#define DD 1024
#define HH 16
#define KVH 4
#define HDD 64
#define EE 16
#define II 1408
#define TT (BB*SS)
#define EPS_ 1e-6f

__device__ __forceinline__ float wred_sum(float v) {
#pragma unroll
  for (int o = 32; o > 0; o >>= 1) v += __shfl_xor(v, o);
  return v;
}

// transposed A-tile scatter store: As[k][m]
#define ASTORE(AS, av) \
  AS[ac4+0][arow]=av.x; AS[ac4+1][arow]=av.y; AS[ac4+2][arow]=av.z; AS[ac4+3][arow]=av.w;

#define INNER16(AS, BS, ACC) \
  _Pragma("unroll") \
  for (int kk_ = 0; kk_ < 16; ++kk_) { \
    float4 a4_ = *(const float4*)&AS[kk_][ty*4]; \
    float4 b4_ = *(const float4*)&BS[kk_][tx*4]; \
    float aa_[4] = {a4_.x, a4_.y, a4_.z, a4_.w}; \
    float bb_[4] = {b4_.x, b4_.y, b4_.z, b4_.w}; \
    _Pragma("unroll") \
    for (int i_ = 0; i_ < 4; ++i_) \
      _Pragma("unroll") \
      for (int j_ = 0; j_ < 4; ++j_) \
        ACC[i_][j_] = fmaf(aa_[i_], bb_[j_], ACC[i_][j_]); \
  }

// ---------------- rmsnorm over D=1024 ----------------
__global__ __launch_bounds__(256) void k_rmsnorm(const float* __restrict__ x,
                                                 const float* __restrict__ w,
                                                 float* __restrict__ out) {
  int row = blockIdx.x, tid = threadIdx.x;
  float4 v = ((const float4*)(x + (size_t)row * DD))[tid];
  float ss = v.x*v.x + v.y*v.y + v.z*v.z + v.w*v.w;
  ss = wred_sum(ss);
  __shared__ float red[4];
  if ((tid & 63) == 0) red[tid >> 6] = ss;
  __syncthreads();
  float tot = red[0] + red[1] + red[2] + red[3];
  float sc = rsqrtf(tot * (1.0f / DD) + EPS_);
  float4 wv = ((const float4*)w)[tid];
  float4 o = make_float4(v.x*sc*wv.x, v.y*sc*wv.y, v.z*sc*wv.z, v.w*sc*wv.w);
  ((float4*)(out + (size_t)row * DD))[tid] = o;
}

// ---------------- fused QKV GEMM: h(2048x1024) @ {wq,wk,wv} ----------------
__global__ __launch_bounds__(256) void k_qkv(const float* __restrict__ h,
    const float* __restrict__ wq, const float* __restrict__ wk, const float* __restrict__ wv,
    float* __restrict__ qb, float* __restrict__ kb, float* __restrict__ vb) {
  int nt = blockIdx.x, m0 = blockIdx.y * 64;
  const float* Bm; float* Cm; int Nm, n0;
  if (nt < 16)      { Bm = wq; Cm = qb; Nm = 1024; n0 = nt * 64; }
  else if (nt < 20) { Bm = wk; Cm = kb; Nm = 256;  n0 = (nt - 16) * 64; }
  else              { Bm = wv; Cm = vb; Nm = 256;  n0 = (nt - 20) * 64; }
  __shared__ __align__(16) float As[16][64];
  __shared__ __align__(16) float Bs[16][64];
  int tid = threadIdx.x, tx = tid & 15, ty = tid >> 4;
  int arow = tid >> 2, ac4 = (tid & 3) * 4, brow = tid >> 4, bn4 = (tid & 15) * 4;
  float acc[4][4] = {};
  for (int k0 = 0; k0 < DD; k0 += 16) {
    float4 av = *(const float4*)&h[(size_t)(m0 + arow) * DD + k0 + ac4];
    ASTORE(As, av)
    float4 bv = *(const float4*)&Bm[(size_t)(k0 + brow) * Nm + n0 + bn4];
    *(float4*)&Bs[brow][bn4] = bv;
    __syncthreads();
    INNER16(As, Bs, acc)
    __syncthreads();
  }
#pragma unroll
  for (int i = 0; i < 4; ++i) {
    float4 o = make_float4(acc[i][0], acc[i][1], acc[i][2], acc[i][3]);
    *(float4*)&Cm[(size_t)(m0 + ty*4 + i) * Nm + n0 + tx*4] = o;
  }
}

// ---------------- per-head q/k rmsnorm + rope (in place) ----------------
__global__ __launch_bounds__(256) void k_qknorm_rope(float* __restrict__ qb, float* __restrict__ kb,
    const float* __restrict__ qnw, const float* __restrict__ knw,
    const float* __restrict__ cosb, const float* __restrict__ sinb) {
  int tok = blockIdx.x, grp = blockIdx.y;       // grp 0..3: q heads, grp 4: k heads
  int wv = threadIdx.x >> 6, d = threadIdx.x & 63;
  int s = tok & (SS - 1);
  float* ptr; const float* wn;
  if (grp < 4) { ptr = qb + (size_t)tok * 1024 + (grp * 4 + wv) * 64; wn = qnw; }
  else         { ptr = kb + (size_t)tok * 256 + wv * 64;              wn = knw; }
  float v = ptr[d];
  float ssum = wred_sum(v * v);
  float rms = rsqrtf(ssum * (1.0f / 64.0f) + EPS_);
  float nv = v * rms * wn[d];
  float pn = __shfl_xor(nv, 32);
  float rot = (d < 32) ? -pn : pn;
  ptr[d] = nv * cosb[s * 64 + d] + rot * sinb[s * 64 + d];
}

// ---------------- scores: S[q][k] = 0.125 * q . k  (causal tiles only) ----------------
__global__ __launch_bounds__(256) void k_scores(const float* __restrict__ qb,
    const float* __restrict__ kb, float* __restrict__ sc, int bh0) {
  int kt = blockIdx.x, qt = blockIdx.y;
  if (kt > qt) return;
  int bh = bh0 + blockIdx.z;
  int b = bh >> 4, hh = bh & 15, kv = hh >> 2;
  int q0 = qt * 64, k0 = kt * 64;
  __shared__ __align__(16) float Qs[16][64];
  __shared__ __align__(16) float Ks[16][64];
  int tid = threadIdx.x, tx = tid & 15, ty = tid >> 4;
  int arow = tid >> 2, ac4 = (tid & 3) * 4;
  float acc[4][4] = {};
  const float* qbase = qb + (size_t)b * SS * 1024 + hh * 64;
  const float* kbase = kb + (size_t)b * SS * 256 + kv * 64;
#pragma unroll
  for (int d0 = 0; d0 < 64; d0 += 16) {
    float4 av = *(const float4*)&qbase[(size_t)(q0 + arow) * 1024 + d0 + ac4];
    ASTORE(Qs, av)
    float4 bv = *(const float4*)&kbase[(size_t)(k0 + arow) * 256 + d0 + ac4];
    Ks[ac4+0][arow]=bv.x; Ks[ac4+1][arow]=bv.y; Ks[ac4+2][arow]=bv.z; Ks[ac4+3][arow]=bv.w;
    __syncthreads();
    INNER16(Qs, Ks, acc)
    __syncthreads();
  }
  float* srow = sc + (size_t)blockIdx.z * SS * SS;
#pragma unroll
  for (int i = 0; i < 4; ++i) {
    float4 o = make_float4(acc[i][0]*0.125f, acc[i][1]*0.125f, acc[i][2]*0.125f, acc[i][3]*0.125f);
    *(float4*)&srow[(size_t)(q0 + ty*4 + i) * SS + k0 + tx*4] = o;
  }
}

// ---------------- row softmax over k<=q, zeros beyond ----------------
__global__ __launch_bounds__(256) void k_softmax(float* __restrict__ sc) {
  int q = blockIdx.x;
  float* row = sc + (size_t)blockIdx.y * SS * SS + (size_t)q * SS;
  int n = q + 1, tid = threadIdx.x;
  float m = -3.4e38f;
  for (int i = tid; i < n; i += 256) m = fmaxf(m, row[i]);
#pragma unroll
  for (int o = 32; o > 0; o >>= 1) m = fmaxf(m, __shfl_xor(m, o));
  __shared__ float redm[4], reds[4];
  if ((tid & 63) == 0) redm[tid >> 6] = m;
  __syncthreads();
  m = fmaxf(fmaxf(redm[0], redm[1]), fmaxf(redm[2], redm[3]));
  float l = 0.f;
  for (int i = tid; i < n; i += 256) { float e = __expf(row[i] - m); row[i] = e; l += e; }
  l = wred_sum(l);
  if ((tid & 63) == 0) reds[tid >> 6] = l;
  __syncthreads();
  l = reds[0] + reds[1] + reds[2] + reds[3];
  float inv = 1.0f / l;
  for (int i = tid; i < n; i += 256) row[i] *= inv;
  for (int i = n + tid; i < SS; i += 256) row[i] = 0.0f;
}

// ---------------- PV: attn[q][d] = sum_k P[q][k] V[k][d] ----------------
__global__ __launch_bounds__(256) void k_pv(const float* __restrict__ sc,
    const float* __restrict__ vb, float* __restrict__ attn, int bh0) {
  int qt = blockIdx.x;
  int bh = bh0 + blockIdx.y;
  int b = bh >> 4, hh = bh & 15, kv = hh >> 2;
  int m0 = qt * 64;
  const float* P = sc + (size_t)blockIdx.y * SS * SS;
  const float* vbase = vb + (size_t)b * SS * 256 + kv * 64;
  __shared__ __align__(16) float As[16][64];
  __shared__ __align__(16) float Bs[16][64];
  int tid = threadIdx.x, tx = tid & 15, ty = tid >> 4;
  int arow = tid >> 2, ac4 = (tid & 3) * 4, brow = tid >> 4, bn4 = (tid & 15) * 4;
  float acc[4][4] = {};
  int kend = m0 + 64;   // causal: P is zero beyond q
  for (int k0 = 0; k0 < kend; k0 += 16) {
    float4 av = *(const float4*)&P[(size_t)(m0 + arow) * SS + k0 + ac4];
    ASTORE(As, av)
    float4 bv = *(const float4*)&vbase[(size_t)(k0 + brow) * 256 + bn4];
    *(float4*)&Bs[brow][bn4] = bv;
    __syncthreads();
    INNER16(As, Bs, acc)
    __syncthreads();
  }
#pragma unroll
  for (int i = 0; i < 4; ++i) {
    float4 o = make_float4(acc[i][0], acc[i][1], acc[i][2], acc[i][3]);
    *(float4*)&attn[(size_t)(b * SS + m0 + ty*4 + i) * 1024 + hh * 64 + tx*4] = o;
  }
}

// ---------------- Wo GEMM + residual: x2 = attn @ wo + x ----------------
__global__ __launch_bounds__(256) void k_wo(const float* __restrict__ attn,
    const float* __restrict__ wo, const float* __restrict__ x, float* __restrict__ x2) {
  int n0 = blockIdx.x * 64, m0 = blockIdx.y * 64;
  __shared__ __align__(16) float As[16][64];
  __shared__ __align__(16) float Bs[16][64];
  int tid = threadIdx.x, tx = tid & 15, ty = tid >> 4;
  int arow = tid >> 2, ac4 = (tid & 3) * 4, brow = tid >> 4, bn4 = (tid & 15) * 4;
  float acc[4][4] = {};
  for (int k0 = 0; k0 < DD; k0 += 16) {
    float4 av = *(const float4*)&attn[(size_t)(m0 + arow) * DD + k0 + ac4];
    ASTORE(As, av)
    float4 bv = *(const float4*)&wo[(size_t)(k0 + brow) * DD + n0 + bn4];
    *(float4*)&Bs[brow][bn4] = bv;
    __syncthreads();
    INNER16(As, Bs, acc)
    __syncthreads();
  }
#pragma unroll
  for (int i = 0; i < 4; ++i) {
    int row = m0 + ty*4 + i;
    float4 xr = *(const float4*)&x[(size_t)row * DD + n0 + tx*4];
    float4 o = make_float4(acc[i][0] + xr.x, acc[i][1] + xr.y, acc[i][2] + xr.z, acc[i][3] + xr.w);
    *(float4*)&x2[(size_t)row * DD + n0 + tx*4] = o;
  }
}

// ---------------- router: logits, softmax16, top2, expert lists ----------------
__global__ __launch_bounds__(256) void k_router(const float* __restrict__ tb,
    const float* __restrict__ rw, int* __restrict__ cnt, int* __restrict__ listTok,
    int* __restrict__ tokslot, float* __restrict__ topw, float* __restrict__ psum) {
  int tok = blockIdx.x, tid = threadIdx.x;
  __shared__ __align__(16) float tl[1024];
  __shared__ float part[16][16];
  __shared__ float lg[16];
  ((float4*)tl)[tid] = ((const float4*)(tb + (size_t)tok * DD))[tid];
  __syncthreads();
  int e = tid & 15, ch = tid >> 4;
  float p = 0.f;
#pragma unroll 8
  for (int j = 0; j < 64; ++j) p = fmaf(tl[ch * 64 + j], rw[(ch * 64 + j) * EE + e], p);
  part[ch][e] = p;
  __syncthreads();
  if (tid < 16) {
    float s = 0.f;
#pragma unroll
    for (int c = 0; c < 16; ++c) s += part[c][tid];
    lg[tid] = s;
  }
  __syncthreads();
  if (tid == 0) {
    float mx = lg[0];
    for (int i = 1; i < 16; ++i) mx = fmaxf(mx, lg[i]);
    float pr[16]; float s = 0.f;
    for (int i = 0; i < 16; ++i) { pr[i] = __expf(lg[i] - mx); s += pr[i]; }
    float inv = 1.0f / s;
    for (int i = 0; i < 16; ++i) pr[i] *= inv;
    int i1 = 0; float v1 = pr[0];
    for (int i = 1; i < 16; ++i) if (pr[i] > v1) { v1 = pr[i]; i1 = i; }
    int i2 = -1; float v2 = -1.f;
    for (int i = 0; i < 16; ++i) if (i != i1 && pr[i] > v2) { v2 = pr[i]; i2 = i; }
    float wsum = v1 + v2;
    int p1 = atomicAdd(&cnt[i1], 1);
    int p2 = atomicAdd(&cnt[i2], 1);
    listTok[i1 * 2048 + p1] = tok;
    listTok[i2 * 2048 + p2] = tok;
    tokslot[tok * 2 + 0] = i1 * 2048 + p1;
    tokslot[tok * 2 + 1] = i2 * 2048 + p2;
    topw[tok * 2 + 0] = v1 / wsum;
    topw[tok * 2 + 1] = v2 / wsum;
    for (int i = 0; i < 16; ++i) atomicAdd(&psum[i], pr[i]);
  }
}

__global__ void k_zero(int* cnt, float* psum) {
  int t = threadIdx.x;
  if (t < 16) { cnt[t] = 0; psum[t] = 0.f; }
}

__global__ void k_prefix(const int* __restrict__ cnt, int* __restrict__ offs) {
  if (threadIdx.x == 0) {
    int s = 0;
    for (int e = 0; e < 16; ++e) { offs[e] = s; s += cnt[e]; }
  }
}

// ---------------- grouped gate/up GEMM + silu*up ----------------
__global__ __launch_bounds__(256) void k_gateup(const float* __restrict__ tb,
    const float* __restrict__ wg, const float* __restrict__ wu,
    const int* __restrict__ cnt, const int* __restrict__ offs,
    const int* __restrict__ listTok, float* __restrict__ act) {
  int e = blockIdx.z;
  int ce = cnt[e];
  int m0 = blockIdx.y * 64;
  if (m0 >= ce) return;
  int n0 = blockIdx.x * 64;
  __shared__ __align__(16) float As[16][64];
  __shared__ __align__(16) float Gs[16][64];
  __shared__ __align__(16) float Us[16][64];
  __shared__ int rows[64];
  int tid = threadIdx.x;
  if (tid < 64) {
    int m = m0 + tid; if (m >= ce) m = ce - 1;
    rows[tid] = listTok[e * 2048 + m];
  }
  __syncthreads();
  int tx = tid & 15, ty = tid >> 4, arow = tid >> 2, ac4 = (tid & 3) * 4;
  int brow = tid >> 4, bn4 = (tid & 15) * 4;
  const float* wge = wg + (size_t)e * DD * II + n0;
  const float* wue = wu + (size_t)e * DD * II + n0;
  const float* arp = tb + (size_t)rows[arow] * DD;
  float accg[4][4] = {}, accu[4][4] = {};
  for (int k0 = 0; k0 < DD; k0 += 16) {
    float4 av = *(const float4*)&arp[k0 + ac4];
    ASTORE(As, av)
    float4 gv = *(const float4*)&wge[(size_t)(k0 + brow) * II + bn4];
    *(float4*)&Gs[brow][bn4] = gv;
    float4 uv = *(const float4*)&wue[(size_t)(k0 + brow) * II + bn4];
    *(float4*)&Us[brow][bn4] = uv;
    __syncthreads();
#pragma unroll
    for (int kk = 0; kk < 16; ++kk) {
      float4 a4 = *(const float4*)&As[kk][ty*4];
      float4 g4 = *(const float4*)&Gs[kk][tx*4];
      float4 u4 = *(const float4*)&Us[kk][tx*4];
      float aa[4] = {a4.x, a4.y, a4.z, a4.w};
      float gg[4] = {g4.x, g4.y, g4.z, g4.w};
      float uu[4] = {u4.x, u4.y, u4.z, u4.w};
#pragma unroll
      for (int i = 0; i < 4; ++i)
#pragma unroll
        for (int j = 0; j < 4; ++j) {
          accg[i][j] = fmaf(aa[i], gg[j], accg[i][j]);
          accu[i][j] = fmaf(aa[i], uu[j], accu[i][j]);
        }
    }
    __syncthreads();
  }
  int ob = offs[e];
#pragma unroll
  for (int i = 0; i < 4; ++i) {
    int m = m0 + ty*4 + i;
    if (m < ce) {
      float4 o;
      float g, u;
      g = accg[i][0]; u = accu[i][0]; o.x = (g / (1.f + __expf(-g))) * u;
      g = accg[i][1]; u = accu[i][1]; o.y = (g / (1.f + __expf(-g))) * u;
      g = accg[i][2]; u = accu[i][2]; o.z = (g / (1.f + __expf(-g))) * u;
      g = accg[i][3]; u = accu[i][3]; o.w = (g / (1.f + __expf(-g))) * u;
      *(float4*)&act[(size_t)(ob + m) * II + n0 + tx*4] = o;
    }
  }
}

// ---------------- grouped down GEMM: eo = act @ w_down[e] ----------------
__global__ __launch_bounds__(256) void k_down(const float* __restrict__ act,
    const float* __restrict__ wd, const int* __restrict__ cnt, const int* __restrict__ offs,
    float* __restrict__ eo) {
  int e = blockIdx.z;
  int ce = cnt[e];
  int m0 = blockIdx.y * 64;
  if (m0 >= ce) return;
  int n0 = blockIdx.x * 64;
  __shared__ __align__(16) float As[16][64];
  __shared__ __align__(16) float Bs[16][64];
  int tid = threadIdx.x, tx = tid & 15, ty = tid >> 4;
  int arow = tid >> 2, ac4 = (tid & 3) * 4, brow = tid >> 4, bn4 = (tid & 15) * 4;
  int ob = offs[e];
  int mr = m0 + arow; if (mr >= ce) mr = ce - 1;
  const float* arp = act + (size_t)(ob + mr) * II;
  const float* wde = wd + (size_t)e * II * DD;
  float acc[4][4] = {};
  for (int k0 = 0; k0 < II; k0 += 16) {
    float4 av = *(const float4*)&arp[k0 + ac4];
    ASTORE(As, av)
    float4 bv = *(const float4*)&wde[(size_t)(k0 + brow) * DD + n0 + bn4];
    *(float4*)&Bs[brow][bn4] = bv;
    __syncthreads();
    INNER16(As, Bs, acc)
    __syncthreads();
  }
#pragma unroll
  for (int i = 0; i < 4; ++i) {
    int m = m0 + ty*4 + i;
    if (m < ce) {
      float4 o = make_float4(acc[i][0], acc[i][1], acc[i][2], acc[i][3]);
      *(float4*)&eo[(size_t)(ob + m) * DD + n0 + tx*4] = o;
    }
  }
}

// ---------------- final: out = x2 + w0*eo[slot0] + w1*eo[slot1]; ----------------
__global__ __launch_bounds__(256) void k_final(const float* __restrict__ x2,
    const float* __restrict__ eo, const int* __restrict__ tokslot,
    const float* __restrict__ topw, const int* __restrict__ offs, float* __restrict__ out) {
  int tok = blockIdx.x, tid = threadIdx.x;
  int c0 = tokslot[tok * 2], c1 = tokslot[tok * 2 + 1];
  int s0 = offs[c0 >> 11] + (c0 & 2047);
  int s1 = offs[c1 >> 11] + (c1 & 2047);
  float w0 = topw[tok * 2], w1 = topw[tok * 2 + 1];
  float4 a = ((const float4*)(x2 + (size_t)tok * DD))[tid];
  float4 e0 = ((const float4*)(eo + (size_t)s0 * DD))[tid];
  float4 e1 = ((const float4*)(eo + (size_t)s1 * DD))[tid];
  float4 o = make_float4(a.x + w0*e0.x + w1*e1.x, a.y + w0*e0.y + w1*e1.y,
                         a.z + w0*e0.z + w1*e1.z, a.w + w0*e0.w + w1*e1.w);
  ((float4*)(out + (size_t)tok * DD))[tid] = o;
}

__global__ void k_aux(const int* __restrict__ cnt, const float* __restrict__ psum,
                      float* __restrict__ out) {
  if (threadIdx.x == 0) {
    float a = 0.f;
    for (int e = 0; e < 16; ++e)
      a += ((float)cnt[e] * (1.0f / 4096.0f)) * (psum[e] * (1.0f / 2048.0f));
    out[(size_t)TT * DD] = 16.0f * a;
  }
}

extern "C" void kernel_launch(void* const* d_in, const int* in_sizes, int n_in,
                              void* d_out, int out_size, void* d_ws, size_t ws_size,
                              hipStream_t stream) {
  const float* x    = (const float*)d_in[0];
  const float* cosb = (const float*)d_in[1];
  const float* sinb = (const float*)d_in[2];
  const float* ln1w = (const float*)d_in[3];
  const float* wq   = (const float*)d_in[4];
  const float* wk   = (const float*)d_in[5];
  const float* wv   = (const float*)d_in[6];
  const float* wo   = (const float*)d_in[7];
  const float* qnw  = (const float*)d_in[8];
  const float* knw  = (const float*)d_in[9];
  const float* ln2w = (const float*)d_in[10];
  const float* rw   = (const float*)d_in[11];
  const float* wg   = (const float*)d_in[12];
  const float* wu   = (const float*)d_in[13];
  const float* wd   = (const float*)d_in[14];
  float* out = (float*)d_out;

  float* W = (float*)d_ws;
  int*   cnt     = (int*)W;                 // 16
  int*   offs    = (int*)(W + 16);          // 16
  float* psum    = W + 32;                  // 16
  int*   tokslot = (int*)(W + 64);          // 4096
  float* topw    = W + 64 + 4096;           // 4096
  int*   listTok = (int*)(W + 64 + 8192);   // 16*2048
  size_t o = 65536;
  float* h    = W + o; o += (size_t)TT * DD;
  float* qb   = W + o; o += (size_t)TT * 1024;
  float* kb   = W + o; o += (size_t)TT * 256;
  float* vb   = W + o; o += (size_t)TT * 256;
  float* attn = W + o; o += (size_t)TT * 1024;
  float* x2   = W + o; o += (size_t)TT * DD;
  float* tb   = W + o; o += (size_t)TT * DD;
  float* act  = W + o; o += (size_t)4096 * II;
  float* eo   = W + o; o += (size_t)4096 * DD;
  float* sc   = W + o;
  long avail = (long)(ws_size / 4) - (long)o;
  int NC = (int)(avail / ((long)SS * SS));
  if (NC > 32) NC = 32;
  if (NC < 1) NC = 1;

  k_zero<<<1, 64, 0, stream>>>(cnt, psum);
  k_rmsnorm<<<TT, 256, 0, stream>>>(x, ln1w, h);
  k_qkv<<<dim3(24, 32), 256, 0, stream>>>(h, wq, wk, wv, qb, kb, vb);
  k_qknorm_rope<<<dim3(TT, 5), 256, 0, stream>>>(qb, kb, qnw, knw, cosb, sinb);
  for (int bh0 = 0; bh0 < 32; bh0 += NC) {
    int nc = 32 - bh0; if (nc > NC) nc = NC;
    k_scores<<<dim3(16, 16, nc), 256, 0, stream>>>(qb, kb, sc, bh0);
    k_softmax<<<dim3(SS, nc), 256, 0, stream>>>(sc);
    k_pv<<<dim3(16, nc), 256, 0, stream>>>(sc, vb, attn, bh0);
  }
  k_wo<<<dim3(16, 32), 256, 0, stream>>>(attn, wo, x, x2);
  k_rmsnorm<<<TT, 256, 0, stream>>>(x2, ln2w, tb);
  k_router<<<TT, 256, 0, stream>>>(tb, rw, cnt, listTok, tokslot, topw, psum);
  k_prefix<<<1, 1, 0, stream>>>(cnt, offs);
  k_gateup<<<dim3(22, 32, 16), 256, 0, stream>>>(tb, wg, wu, cnt, offs, listTok, act);
  k_down<<<dim3(16, 32, 16), 256, 0, stream>>>(act, wd, cnt, offs, eo);
  k_final<<<TT, 256, 0, stream>>>(x2, eo, tokslot, topw, offs, out);
  k_aux<<<1, 1, 0, stream>>>(cnt, psum, out);
}

// Round 2
// 572.646 us; speedup vs baseline: 2.6096x; 2.6096x over previous
//
#include <hip/hip_runtime.h>

#define BB 2
#define SS 1024
#define DD 1024
#define HH 16
#define KVH 4
#define HDD 64
#define EE 16
#define II 1408
#define TT (BB*SS)
#define EPS_ 1e-6f

typedef unsigned short u16;
typedef __bf16 bf16x8 __attribute__((ext_vector_type(8)));
typedef float f32x4 __attribute__((ext_vector_type(4)));

__device__ __forceinline__ float wred_sum(float v) {
#pragma unroll
  for (int o = 32; o > 0; o >>= 1) v += __shfl_xor(v, o);
  return v;
}

__device__ __forceinline__ u16 f2b(float f) {
  __bf16 h = (__bf16)f;
  return __builtin_bit_cast(u16, h);
}

__device__ __forceinline__ bf16x8 ld_frag(const u16* p) {
  return __builtin_bit_cast(bf16x8, *(const uint4*)p);
}

// transposed A-tile scatter store: As[k][m]
#define ASTORE(AS, av) \
  AS[ac4+0][arow]=av.x; AS[ac4+1][arow]=av.y; AS[ac4+2][arow]=av.z; AS[ac4+3][arow]=av.w;

#define INNER16(AS, BS, ACC) \
  _Pragma("unroll") \
  for (int kk_ = 0; kk_ < 16; ++kk_) { \
    float4 a4_ = *(const float4*)&AS[kk_][ty*4]; \
    float4 b4_ = *(const float4*)&BS[kk_][tx*4]; \
    float aa_[4] = {a4_.x, a4_.y, a4_.z, a4_.w}; \
    float bb_[4] = {b4_.x, b4_.y, b4_.z, b4_.w}; \
    _Pragma("unroll") \
    for (int i_ = 0; i_ < 4; ++i_) \
      _Pragma("unroll") \
      for (int j_ = 0; j_ < 4; ++j_) \
        ACC[i_][j_] = fmaf(aa_[i_], bb_[j_], ACC[i_][j_]); \
  }

// ---------------- rmsnorm over D=1024 ----------------
__global__ __launch_bounds__(256) void k_rmsnorm(const float* __restrict__ x,
                                                 const float* __restrict__ w,
                                                 float* __restrict__ out) {
  int row = blockIdx.x, tid = threadIdx.x;
  float4 v = ((const float4*)(x + (size_t)row * DD))[tid];
  float ss = v.x*v.x + v.y*v.y + v.z*v.z + v.w*v.w;
  ss = wred_sum(ss);
  __shared__ float red[4];
  if ((tid & 63) == 0) red[tid >> 6] = ss;
  __syncthreads();
  float tot = red[0] + red[1] + red[2] + red[3];
  float sc = rsqrtf(tot * (1.0f / DD) + EPS_);
  float4 wv = ((const float4*)w)[tid];
  float4 o = make_float4(v.x*sc*wv.x, v.y*sc*wv.y, v.z*sc*wv.z, v.w*sc*wv.w);
  ((float4*)(out + (size_t)row * DD))[tid] = o;
}

// ---------------- fp32 -> bf16 bulk convert ----------------
__global__ __launch_bounds__(256) void k_tobf16(const float* __restrict__ in,
                                                u16* __restrict__ out, int n4) {
  int i = blockIdx.x * 256 + threadIdx.x;
  if (i < n4) {
    float4 v = ((const float4*)in)[i];
    ushort4 o = make_ushort4(f2b(v.x), f2b(v.y), f2b(v.z), f2b(v.w));
    ((ushort4*)out)[i] = o;
  }
}

// ---------------- fused QKV GEMM ----------------
__global__ __launch_bounds__(256) void k_qkv(const float* __restrict__ h,
    const float* __restrict__ wq, const float* __restrict__ wk, const float* __restrict__ wv,
    float* __restrict__ qb, float* __restrict__ kb, float* __restrict__ vb) {
  int nt = blockIdx.x, m0 = blockIdx.y * 64;
  const float* Bm; float* Cm; int Nm, n0;
  if (nt < 16)      { Bm = wq; Cm = qb; Nm = 1024; n0 = nt * 64; }
  else if (nt < 20) { Bm = wk; Cm = kb; Nm = 256;  n0 = (nt - 16) * 64; }
  else              { Bm = wv; Cm = vb; Nm = 256;  n0 = (nt - 20) * 64; }
  __shared__ __align__(16) float As[16][64];
  __shared__ __align__(16) float Bs[16][64];
  int tid = threadIdx.x, tx = tid & 15, ty = tid >> 4;
  int arow = tid >> 2, ac4 = (tid & 3) * 4, brow = tid >> 4, bn4 = (tid & 15) * 4;
  float acc[4][4] = {};
  for (int k0 = 0; k0 < DD; k0 += 16) {
    float4 av = *(const float4*)&h[(size_t)(m0 + arow) * DD + k0 + ac4];
    ASTORE(As, av)
    float4 bv = *(const float4*)&Bm[(size_t)(k0 + brow) * Nm + n0 + bn4];
    *(float4*)&Bs[brow][bn4] = bv;
    __syncthreads();
    INNER16(As, Bs, acc)
    __syncthreads();
  }
#pragma unroll
  for (int i = 0; i < 4; ++i) {
    float4 o = make_float4(acc[i][0], acc[i][1], acc[i][2], acc[i][3]);
    *(float4*)&Cm[(size_t)(m0 + ty*4 + i) * Nm + n0 + tx*4] = o;
  }
}

// ---------------- per-head q/k rmsnorm + rope (in place) ----------------
__global__ __launch_bounds__(256) void k_qknorm_rope(float* __restrict__ qb, float* __restrict__ kb,
    const float* __restrict__ qnw, const float* __restrict__ knw,
    const float* __restrict__ cosb, const float* __restrict__ sinb) {
  int tok = blockIdx.x, grp = blockIdx.y;
  int wv = threadIdx.x >> 6, d = threadIdx.x & 63;
  int s = tok & (SS - 1);
  float* ptr; const float* wn;
  if (grp < 4) { ptr = qb + (size_t)tok * 1024 + (grp * 4 + wv) * 64; wn = qnw; }
  else         { ptr = kb + (size_t)tok * 256 + wv * 64;              wn = knw; }
  float v = ptr[d];
  float ssum = wred_sum(v * v);
  float rms = rsqrtf(ssum * (1.0f / 64.0f) + EPS_);
  float nv = v * rms * wn[d];
  float pn = __shfl_xor(nv, 32);
  float rot = (d < 32) ? -pn : pn;
  ptr[d] = nv * cosb[s * 64 + d] + rot * sinb[s * 64 + d];
}

// ---------------- scores ----------------
__global__ __launch_bounds__(256) void k_scores(const float* __restrict__ qb,
    const float* __restrict__ kb, float* __restrict__ sc, int bh0) {
  int kt = blockIdx.x, qt = blockIdx.y;
  if (kt > qt) return;
  int bh = bh0 + blockIdx.z;
  int b = bh >> 4, hh = bh & 15, kv = hh >> 2;
  int q0 = qt * 64, k0 = kt * 64;
  __shared__ __align__(16) float Qs[16][64];
  __shared__ __align__(16) float Ks[16][64];
  int tid = threadIdx.x, tx = tid & 15, ty = tid >> 4;
  int arow = tid >> 2, ac4 = (tid & 3) * 4;
  float acc[4][4] = {};
  const float* qbase = qb + (size_t)b * SS * 1024 + hh * 64;
  const float* kbase = kb + (size_t)b * SS * 256 + kv * 64;
#pragma unroll
  for (int d0 = 0; d0 < 64; d0 += 16) {
    float4 av = *(const float4*)&qbase[(size_t)(q0 + arow) * 1024 + d0 + ac4];
    ASTORE(Qs, av)
    float4 bv = *(const float4*)&kbase[(size_t)(k0 + arow) * 256 + d0 + ac4];
    Ks[ac4+0][arow]=bv.x; Ks[ac4+1][arow]=bv.y; Ks[ac4+2][arow]=bv.z; Ks[ac4+3][arow]=bv.w;
    __syncthreads();
    INNER16(Qs, Ks, acc)
    __syncthreads();
  }
  float* srow = sc + (size_t)blockIdx.z * SS * SS;
#pragma unroll
  for (int i = 0; i < 4; ++i) {
    float4 o = make_float4(acc[i][0]*0.125f, acc[i][1]*0.125f, acc[i][2]*0.125f, acc[i][3]*0.125f);
    *(float4*)&srow[(size_t)(q0 + ty*4 + i) * SS + k0 + tx*4] = o;
  }
}

// ---------------- row softmax ----------------
__global__ __launch_bounds__(256) void k_softmax(float* __restrict__ sc) {
  int q = blockIdx.x;
  float* row = sc + (size_t)blockIdx.y * SS * SS + (size_t)q * SS;
  int n = q + 1, tid = threadIdx.x;
  float m = -3.4e38f;
  for (int i = tid; i < n; i += 256) m = fmaxf(m, row[i]);
#pragma unroll
  for (int o = 32; o > 0; o >>= 1) m = fmaxf(m, __shfl_xor(m, o));
  __shared__ float redm[4], reds[4];
  if ((tid & 63) == 0) redm[tid >> 6] = m;
  __syncthreads();
  m = fmaxf(fmaxf(redm[0], redm[1]), fmaxf(redm[2], redm[3]));
  float l = 0.f;
  for (int i = tid; i < n; i += 256) { float e = __expf(row[i] - m); row[i] = e; l += e; }
  l = wred_sum(l);
  if ((tid & 63) == 0) reds[tid >> 6] = l;
  __syncthreads();
  l = reds[0] + reds[1] + reds[2] + reds[3];
  float inv = 1.0f / l;
  for (int i = tid; i < n; i += 256) row[i] *= inv;
  for (int i = n + tid; i < SS; i += 256) row[i] = 0.0f;
}

// ---------------- PV ----------------
__global__ __launch_bounds__(256) void k_pv(const float* __restrict__ sc,
    const float* __restrict__ vb, float* __restrict__ attn, int bh0) {
  int qt = blockIdx.x;
  int bh = bh0 + blockIdx.y;
  int b = bh >> 4, hh = bh & 15, kv = hh >> 2;
  int m0 = qt * 64;
  const float* P = sc + (size_t)blockIdx.y * SS * SS;
  const float* vbase = vb + (size_t)b * SS * 256 + kv * 64;
  __shared__ __align__(16) float As[16][64];
  __shared__ __align__(16) float Bs[16][64];
  int tid = threadIdx.x, tx = tid & 15, ty = tid >> 4;
  int arow = tid >> 2, ac4 = (tid & 3) * 4, brow = tid >> 4, bn4 = (tid & 15) * 4;
  float acc[4][4] = {};
  int kend = m0 + 64;
  for (int k0 = 0; k0 < kend; k0 += 16) {
    float4 av = *(const float4*)&P[(size_t)(m0 + arow) * SS + k0 + ac4];
    ASTORE(As, av)
    float4 bv = *(const float4*)&vbase[(size_t)(k0 + brow) * 256 + bn4];
    *(float4*)&Bs[brow][bn4] = bv;
    __syncthreads();
    INNER16(As, Bs, acc)
    __syncthreads();
  }
#pragma unroll
  for (int i = 0; i < 4; ++i) {
    float4 o = make_float4(acc[i][0], acc[i][1], acc[i][2], acc[i][3]);
    *(float4*)&attn[(size_t)(b * SS + m0 + ty*4 + i) * 1024 + hh * 64 + tx*4] = o;
  }
}

// ---------------- Wo GEMM + residual ----------------
__global__ __launch_bounds__(256) void k_wo(const float* __restrict__ attn,
    const float* __restrict__ wo, const float* __restrict__ x, float* __restrict__ x2) {
  int n0 = blockIdx.x * 64, m0 = blockIdx.y * 64;
  __shared__ __align__(16) float As[16][64];
  __shared__ __align__(16) float Bs[16][64];
  int tid = threadIdx.x, tx = tid & 15, ty = tid >> 4;
  int arow = tid >> 2, ac4 = (tid & 3) * 4, brow = tid >> 4, bn4 = (tid & 15) * 4;
  float acc[4][4] = {};
  for (int k0 = 0; k0 < DD; k0 += 16) {
    float4 av = *(const float4*)&attn[(size_t)(m0 + arow) * DD + k0 + ac4];
    ASTORE(As, av)
    float4 bv = *(const float4*)&wo[(size_t)(k0 + brow) * DD + n0 + bn4];
    *(float4*)&Bs[brow][bn4] = bv;
    __syncthreads();
    INNER16(As, Bs, acc)
    __syncthreads();
  }
#pragma unroll
  for (int i = 0; i < 4; ++i) {
    int row = m0 + ty*4 + i;
    float4 xr = *(const float4*)&x[(size_t)row * DD + n0 + tx*4];
    float4 o = make_float4(acc[i][0] + xr.x, acc[i][1] + xr.y, acc[i][2] + xr.z, acc[i][3] + xr.w);
    *(float4*)&x2[(size_t)row * DD + n0 + tx*4] = o;
  }
}

// ---------------- router logits (identical arithmetic to r1 k_router) ----------------
__global__ __launch_bounds__(256) void k_logits(const float* __restrict__ tb,
    const float* __restrict__ rw, float* __restrict__ logits) {
  int tok = blockIdx.x, tid = threadIdx.x;
  __shared__ __align__(16) float tl[1024];
  __shared__ float part[16][16];
  ((float4*)tl)[tid] = ((const float4*)(tb + (size_t)tok * DD))[tid];
  __syncthreads();
  int e = tid & 15, ch = tid >> 4;
  float p = 0.f;
#pragma unroll 8
  for (int j = 0; j < 64; ++j) p = fmaf(tl[ch * 64 + j], rw[(ch * 64 + j) * EE + e], p);
  part[ch][e] = p;
  __syncthreads();
  if (tid < 16) {
    float s = 0.f;
#pragma unroll
    for (int c = 0; c < 16; ++c) s += part[c][tid];
    logits[(size_t)tok * EE + tid] = s;
  }
}

// ---------------- route: softmax16 + top2 per thread; few atomics ----------------
__global__ __launch_bounds__(256) void k_route(const float* __restrict__ logits,
    int* __restrict__ cnt, int* __restrict__ listTok, int* __restrict__ tokslot,
    float* __restrict__ topw, float* __restrict__ psum) {
  int tid = threadIdx.x;
  int tok = blockIdx.x * 256 + tid;
  __shared__ int lcnt[16], gbase[16];
  __shared__ float lps[16];
  if (tid < 16) { lcnt[tid] = 0; lps[tid] = 0.f; }
  __syncthreads();
  float pr[16];
#pragma unroll
  for (int g = 0; g < 4; ++g) {
    float4 v = *(const float4*)&logits[(size_t)tok * EE + g * 4];
    pr[g*4+0] = v.x; pr[g*4+1] = v.y; pr[g*4+2] = v.z; pr[g*4+3] = v.w;
  }
  float mx = pr[0];
#pragma unroll
  for (int i = 1; i < 16; ++i) mx = fmaxf(mx, pr[i]);
  float s = 0.f;
#pragma unroll
  for (int i = 0; i < 16; ++i) { pr[i] = __expf(pr[i] - mx); s += pr[i]; }
  float inv = 1.0f / s;
#pragma unroll
  for (int i = 0; i < 16; ++i) pr[i] *= inv;
  int i1 = 0; float v1 = pr[0];
#pragma unroll
  for (int i = 1; i < 16; ++i) if (pr[i] > v1) { v1 = pr[i]; i1 = i; }
  int i2 = -1; float v2 = -1.f;
#pragma unroll
  for (int i = 0; i < 16; ++i) if (i != i1 && pr[i] > v2) { v2 = pr[i]; i2 = i; }
  float wsum = v1 + v2;
  int lp1 = atomicAdd(&lcnt[i1], 1);
  int lp2 = atomicAdd(&lcnt[i2], 1);
  // psum partial reduce: per-wave shuffle then one LDS atomic per expert per wave
#pragma unroll
  for (int e = 0; e < 16; ++e) {
    float v = wred_sum(pr[e]);
    if ((tid & 63) == 0) atomicAdd(&lps[e], v);
  }
  __syncthreads();
  if (tid < 16) {
    gbase[tid] = atomicAdd(&cnt[tid], lcnt[tid]);
    atomicAdd(&psum[tid], lps[tid]);
  }
  __syncthreads();
  int p1 = gbase[i1] + lp1, p2 = gbase[i2] + lp2;
  listTok[i1 * 2048 + p1] = tok;
  listTok[i2 * 2048 + p2] = tok;
  tokslot[tok * 2 + 0] = i1 * 2048 + p1;
  tokslot[tok * 2 + 1] = i2 * 2048 + p2;
  topw[tok * 2 + 0] = v1 / wsum;
  topw[tok * 2 + 1] = v2 / wsum;
}

__global__ void k_zero(int* cnt, float* psum) {
  int t = threadIdx.x;
  if (t < 16) { cnt[t] = 0; psum[t] = 0.f; }
}

__global__ void k_prefix(const int* __restrict__ cnt, int* __restrict__ offs) {
  if (threadIdx.x == 0) {
    int s = 0;
    for (int e = 0; e < 16; ++e) { offs[e] = s; s += cnt[e]; }
  }
}

// ---------------- MoE gate/up MFMA: tbh(gathered) @ wg/wu[e] -> silu*u -> act(bf16) ----------------
// Mtile=128, Ntile=64, BK=32, 4 waves (2m x 2n)
__global__ __launch_bounds__(256) void k_gu_mfma(const u16* __restrict__ tbh,
    const float* __restrict__ wg, const float* __restrict__ wu,
    const int* __restrict__ cnt, const int* __restrict__ offs,
    const int* __restrict__ listTok, u16* __restrict__ act) {
  int e = blockIdx.z;
  int ce = cnt[e];
  int m0 = blockIdx.y * 128;
  if (m0 >= ce) return;
  int n0 = blockIdx.x * 64;
  __shared__ __align__(16) u16 Ah[128][56];
  __shared__ __align__(16) u16 Gh[64][56];
  __shared__ __align__(16) u16 Uh[64][56];
  __shared__ int rows[128];
  int tid = threadIdx.x;
  if (tid < 128) {
    int m = m0 + tid;
    rows[tid] = listTok[e * 2048 + (m < ce ? m : ce - 1)];
  }
  __syncthreads();
  // staging indices
  int s_arow = tid >> 1, s_acol = (tid & 1) * 16;
  int s_nc = (tid & 31) * 2, s_kg = (tid >> 5) * 4;
  const float* wge = wg + (size_t)e * DD * II + n0;
  const float* wue = wu + (size_t)e * DD * II + n0;
  const u16* ap = tbh + (size_t)rows[s_arow] * DD + s_acol;
  // wave/frag indices
  int lane = tid & 63, w = tid >> 6;
  int wm = (w & 1) * 64, wn = (w >> 1) * 32;
  int lr = lane & 15, lk = (lane >> 4) * 8;
  f32x4 accg[4][2] = {};
  f32x4 accu[4][2] = {};
  for (int k0 = 0; k0 < DD; k0 += 32) {
    uint4 av0 = *(const uint4*)(ap + k0);
    uint4 av1 = *(const uint4*)(ap + k0 + 8);
    float2 g0 = *(const float2*)&wge[(size_t)(k0 + s_kg + 0) * II + s_nc];
    float2 g1 = *(const float2*)&wge[(size_t)(k0 + s_kg + 1) * II + s_nc];
    float2 g2 = *(const float2*)&wge[(size_t)(k0 + s_kg + 2) * II + s_nc];
    float2 g3 = *(const float2*)&wge[(size_t)(k0 + s_kg + 3) * II + s_nc];
    float2 u0 = *(const float2*)&wue[(size_t)(k0 + s_kg + 0) * II + s_nc];
    float2 u1 = *(const float2*)&wue[(size_t)(k0 + s_kg + 1) * II + s_nc];
    float2 u2 = *(const float2*)&wue[(size_t)(k0 + s_kg + 2) * II + s_nc];
    float2 u3 = *(const float2*)&wue[(size_t)(k0 + s_kg + 3) * II + s_nc];
    *(uint4*)&Ah[s_arow][s_acol]     = av0;
    *(uint4*)&Ah[s_arow][s_acol + 8] = av1;
    *(ushort4*)&Gh[s_nc][s_kg]     = make_ushort4(f2b(g0.x), f2b(g1.x), f2b(g2.x), f2b(g3.x));
    *(ushort4*)&Gh[s_nc + 1][s_kg] = make_ushort4(f2b(g0.y), f2b(g1.y), f2b(g2.y), f2b(g3.y));
    *(ushort4*)&Uh[s_nc][s_kg]     = make_ushort4(f2b(u0.x), f2b(u1.x), f2b(u2.x), f2b(u3.x));
    *(ushort4*)&Uh[s_nc + 1][s_kg] = make_ushort4(f2b(u0.y), f2b(u1.y), f2b(u2.y), f2b(u3.y));
    __syncthreads();
    bf16x8 af[4];
#pragma unroll
    for (int fm = 0; fm < 4; ++fm) af[fm] = ld_frag(&Ah[wm + fm*16 + lr][lk]);
#pragma unroll
    for (int nf = 0; nf < 2; ++nf) {
      bf16x8 bg = ld_frag(&Gh[wn + nf*16 + lr][lk]);
      bf16x8 bu = ld_frag(&Uh[wn + nf*16 + lr][lk]);
#pragma unroll
      for (int fm = 0; fm < 4; ++fm) {
        accg[fm][nf] = __builtin_amdgcn_mfma_f32_16x16x32_bf16(af[fm], bg, accg[fm][nf], 0, 0, 0);
        accu[fm][nf] = __builtin_amdgcn_mfma_f32_16x16x32_bf16(af[fm], bu, accu[fm][nf], 0, 0, 0);
      }
    }
    __syncthreads();
  }
  int ob = offs[e];
#pragma unroll
  for (int fm = 0; fm < 4; ++fm)
#pragma unroll
    for (int nf = 0; nf < 2; ++nf)
#pragma unroll
      for (int r = 0; r < 4; ++r) {
        int m = m0 + wm + fm*16 + (lane >> 4) * 4 + r;
        if (m < ce) {
          float g = accg[fm][nf][r], u = accu[fm][nf][r];
          float sv = (g / (1.f + __expf(-g))) * u;
          act[(size_t)(ob + m) * II + n0 + wn + nf*16 + (lane & 15)] = f2b(sv);
        }
      }
}

// ---------------- MoE down MFMA: act(bf16) @ wd[e] -> eo(fp32) ----------------
__global__ __launch_bounds__(256) void k_down_mfma(const u16* __restrict__ act,
    const float* __restrict__ wd, const int* __restrict__ cnt, const int* __restrict__ offs,
    float* __restrict__ eo) {
  int e = blockIdx.z;
  int ce = cnt[e];
  int m0 = blockIdx.y * 128;
  if (m0 >= ce) return;
  int n0 = blockIdx.x * 64;
  __shared__ __align__(16) u16 Ah[128][56];
  __shared__ __align__(16) u16 Bh[64][56];
  int tid = threadIdx.x;
  int ob = offs[e];
  int s_arow = tid >> 1, s_acol = (tid & 1) * 16;
  int s_nc = (tid & 31) * 2, s_kg = (tid >> 5) * 4;
  int mrow = m0 + s_arow; if (mrow >= ce) mrow = ce - 1;
  const u16* ap = act + (size_t)(ob + mrow) * II + s_acol;
  const float* wde = wd + (size_t)e * II * DD + n0;
  int lane = tid & 63, w = tid >> 6;
  int wm = (w & 1) * 64, wn = (w >> 1) * 32;
  int lr = lane & 15, lk = (lane >> 4) * 8;
  f32x4 acc[4][2] = {};
  for (int k0 = 0; k0 < II; k0 += 32) {
    uint4 av0 = *(const uint4*)(ap + k0);
    uint4 av1 = *(const uint4*)(ap + k0 + 8);
    float2 b0 = *(const float2*)&wde[(size_t)(k0 + s_kg + 0) * DD + s_nc];
    float2 b1 = *(const float2*)&wde[(size_t)(k0 + s_kg + 1) * DD + s_nc];
    float2 b2 = *(const float2*)&wde[(size_t)(k0 + s_kg + 2) * DD + s_nc];
    float2 b3 = *(const float2*)&wde[(size_t)(k0 + s_kg + 3) * DD + s_nc];
    *(uint4*)&Ah[s_arow][s_acol]     = av0;
    *(uint4*)&Ah[s_arow][s_acol + 8] = av1;
    *(ushort4*)&Bh[s_nc][s_kg]     = make_ushort4(f2b(b0.x), f2b(b1.x), f2b(b2.x), f2b(b3.x));
    *(ushort4*)&Bh[s_nc + 1][s_kg] = make_ushort4(f2b(b0.y), f2b(b1.y), f2b(b2.y), f2b(b3.y));
    __syncthreads();
    bf16x8 af[4];
#pragma unroll
    for (int fm = 0; fm < 4; ++fm) af[fm] = ld_frag(&Ah[wm + fm*16 + lr][lk]);
#pragma unroll
    for (int nf = 0; nf < 2; ++nf) {
      bf16x8 bb = ld_frag(&Bh[wn + nf*16 + lr][lk]);
#pragma unroll
      for (int fm = 0; fm < 4; ++fm)
        acc[fm][nf] = __builtin_amdgcn_mfma_f32_16x16x32_bf16(af[fm], bb, acc[fm][nf], 0, 0, 0);
    }
    __syncthreads();
  }
#pragma unroll
  for (int fm = 0; fm < 4; ++fm)
#pragma unroll
    for (int nf = 0; nf < 2; ++nf)
#pragma unroll
      for (int r = 0; r < 4; ++r) {
        int m = m0 + wm + fm*16 + (lane >> 4) * 4 + r;
        if (m < ce)
          eo[(size_t)(ob + m) * DD + n0 + wn + nf*16 + (lane & 15)] = acc[fm][nf][r];
      }
}

// ---------------- final combine ----------------
__global__ __launch_bounds__(256) void k_final(const float* __restrict__ x2,
    const float* __restrict__ eo, const int* __restrict__ tokslot,
    const float* __restrict__ topw, const int* __restrict__ offs, float* __restrict__ out) {
  int tok = blockIdx.x, tid = threadIdx.x;
  int c0 = tokslot[tok * 2], c1 = tokslot[tok * 2 + 1];
  int s0 = offs[c0 >> 11] + (c0 & 2047);
  int s1 = offs[c1 >> 11] + (c1 & 2047);
  float w0 = topw[tok * 2], w1 = topw[tok * 2 + 1];
  float4 a = ((const float4*)(x2 + (size_t)tok * DD))[tid];
  float4 e0 = ((const float4*)(eo + (size_t)s0 * DD))[tid];
  float4 e1 = ((const float4*)(eo + (size_t)s1 * DD))[tid];
  float4 o = make_float4(a.x + w0*e0.x + w1*e1.x, a.y + w0*e0.y + w1*e1.y,
                         a.z + w0*e0.z + w1*e1.z, a.w + w0*e0.w + w1*e1.w);
  ((float4*)(out + (size_t)tok * DD))[tid] = o;
}

__global__ void k_aux(const int* __restrict__ cnt, const float* __restrict__ psum,
                      float* __restrict__ out) {
  if (threadIdx.x == 0) {
    float a = 0.f;
    for (int e = 0; e < 16; ++e)
      a += ((float)cnt[e] * (1.0f / 4096.0f)) * (psum[e] * (1.0f / 2048.0f));
    out[(size_t)TT * DD] = 16.0f * a;
  }
}

extern "C" void kernel_launch(void* const* d_in, const int* in_sizes, int n_in,
                              void* d_out, int out_size, void* d_ws, size_t ws_size,
                              hipStream_t stream) {
  const float* x    = (const float*)d_in[0];
  const float* cosb = (const float*)d_in[1];
  const float* sinb = (const float*)d_in[2];
  const float* ln1w = (const float*)d_in[3];
  const float* wq   = (const float*)d_in[4];
  const float* wk   = (const float*)d_in[5];
  const float* wv   = (const float*)d_in[6];
  const float* wo   = (const float*)d_in[7];
  const float* qnw  = (const float*)d_in[8];
  const float* knw  = (const float*)d_in[9];
  const float* ln2w = (const float*)d_in[10];
  const float* rw   = (const float*)d_in[11];
  const float* wg   = (const float*)d_in[12];
  const float* wu   = (const float*)d_in[13];
  const float* wd   = (const float*)d_in[14];
  float* out = (float*)d_out;

  float* W = (float*)d_ws;
  int*   cnt     = (int*)W;                  // 16
  int*   offs    = (int*)(W + 16);           // 16
  float* psum    = W + 32;                   // 16
  int*   tokslot = (int*)(W + 64);           // 4096
  float* topw    = W + 4160;                 // 4096
  int*   listTok = (int*)(W + 8256);         // 32768
  float* logits  = W + 41024;                // 32768
  size_t o = 81920;
  float* h    = W + o; o += (size_t)TT * DD;
  float* qb   = W + o; o += (size_t)TT * 1024;
  float* kb   = W + o; o += (size_t)TT * 256;
  float* vb   = W + o; o += (size_t)TT * 256;
  float* attn = W + o; o += (size_t)TT * 1024;
  float* x2   = W + o; o += (size_t)TT * DD;
  float* tb   = W + o; o += (size_t)TT * DD;
  u16*   tbh  = (u16*)(W + o); o += (size_t)TT * DD / 2;
  u16*   act  = (u16*)(W + o); o += (size_t)4096 * II / 2;
  float* eo   = W + o; o += (size_t)4096 * DD;
  float* sc   = W + o;
  long avail = (long)(ws_size / 4) - (long)o;
  int NC = (int)(avail / ((long)SS * SS));
  if (NC > 32) NC = 32;
  if (NC < 1) NC = 1;

  k_zero<<<1, 64, 0, stream>>>(cnt, psum);
  k_rmsnorm<<<TT, 256, 0, stream>>>(x, ln1w, h);
  k_qkv<<<dim3(24, 32), 256, 0, stream>>>(h, wq, wk, wv, qb, kb, vb);
  k_qknorm_rope<<<dim3(TT, 5), 256, 0, stream>>>(qb, kb, qnw, knw, cosb, sinb);
  for (int bh0 = 0; bh0 < 32; bh0 += NC) {
    int nc = 32 - bh0; if (nc > NC) nc = NC;
    k_scores<<<dim3(16, 16, nc), 256, 0, stream>>>(qb, kb, sc, bh0);
    k_softmax<<<dim3(SS, nc), 256, 0, stream>>>(sc);
    k_pv<<<dim3(16, nc), 256, 0, stream>>>(sc, vb, attn, bh0);
  }
  k_wo<<<dim3(16, 32), 256, 0, stream>>>(attn, wo, x, x2);
  k_rmsnorm<<<TT, 256, 0, stream>>>(x2, ln2w, tb);
  k_tobf16<<<(TT * DD / 4 + 255) / 256, 256, 0, stream>>>(tb, tbh, TT * DD / 4);
  k_logits<<<TT, 256, 0, stream>>>(tb, rw, logits);
  k_route<<<TT / 256, 256, 0, stream>>>(logits, cnt, listTok, tokslot, topw, psum);
  k_prefix<<<1, 1, 0, stream>>>(cnt, offs);
  k_gu_mfma<<<dim3(22, 16, 16), 256, 0, stream>>>(tbh, wg, wu, cnt, offs, listTok, act);
  k_down_mfma<<<dim3(16, 16, 16), 256, 0, stream>>>(act, wd, cnt, offs, eo);
  k_final<<<TT, 256, 0, stream>>>(x2, eo, tokslot, topw, offs, out);
  k_aux<<<1, 1, 0, stream>>>(cnt, psum, out);
}